// Round 3
// baseline (16718.964 us; speedup 1.0000x reference)
//
#include <hip/hip_runtime.h>

#define B_ 128
#define T_ 256
#define IN_ 128
#define G_ 5
#define H_ 512
#define G3_ 1536
#define E_ 1024
#define L_ 256
#define LG_ 251
#define INPG_ 133

#define MU_OFF (B_*T_*IN_)            /* 4194304 */
#define LV_OFF (MU_OFF + B_*LG_)      /* 4226432 */

typedef __attribute__((ext_vector_type(8))) short bf16x8;
typedef __attribute__((ext_vector_type(4))) float f32x4;

__device__ __forceinline__ float bf2f(unsigned short s) {
    return __uint_as_float(((unsigned)s) << 16);
}
__device__ __forceinline__ unsigned short f2bf(float f) {
    unsigned x = __float_as_uint(f);
    unsigned r = (x + 0x7fffu + ((x >> 16) & 1u)) >> 16;
    return (unsigned short)r;
}
__device__ __forceinline__ float sigf(float v) {
    return 1.f / (1.f + __expf(-v));
}

// =============== prep kernels ===============

// x fp32 [B][T][133] -> xb16 [T][B][160] bf16 (cols 133..159 zero)
__global__ void xpad_k(const float* __restrict__ x, ushort* __restrict__ xb) {
    int id = blockIdx.x * 256 + threadIdx.x;
    if (id >= T_ * B_ * 160) return;
    int t = id / (B_ * 160);
    int rem = id - t * (B_ * 160);
    int b = rem / 160, c = rem - b * 160;
    float v = (c < INPG_) ? x[((size_t)b * T_ + t) * INPG_ + c] : 0.f;
    xb[id] = f2bf(v);
}

// encoder weight pack: WE chunks [(dir*32+cb)*63 + ks][64 lanes][8 bf16]
// planes: ks 0..20 r(cat672), 21..41 z(cat672), 42..46 nx(K160), 47..62 nh(K512)
__global__ void pack_we(const float* __restrict__ Wih_f, const float* __restrict__ Whh_f,
                        const float* __restrict__ Wih_b, const float* __restrict__ Whh_b,
                        ushort* __restrict__ WE) {
    int id = blockIdx.x * 256 + threadIdx.x;   // 258048 total
    int lane = id & 63;
    int rest = id >> 6;
    int ks = rest % 63;
    int cb = (rest / 63) & 31;
    int dir = rest / (63 * 32);
    if (dir >= 2) return;
    const float* Wih = dir ? Wih_b : Wih_f;
    const float* Whh = dir ? Whh_b : Whh_f;
    int n = lane & 15, kb = lane >> 4;
    int p, ksp;
    if (ks < 21)      { p = 0; ksp = ks; }
    else if (ks < 42) { p = 1; ksp = ks - 21; }
    else if (ks < 47) { p = 2; ksp = ks - 42; }
    else              { p = 3; ksp = ks - 47; }
    int j = cb * 16 + n;
    int row = (p == 0) ? j : (p == 1) ? 512 + j : 1024 + j;
    #pragma unroll
    for (int e = 0; e < 8; ++e) {
        int k = ksp * 32 + kb * 8 + e;
        float v;
        if (p == 3)      v = Whh[(size_t)row * 512 + k];
        else if (p == 2) v = (k < INPG_) ? Wih[(size_t)row * INPG_ + k] : 0.f;
        else v = (k < INPG_) ? Wih[(size_t)row * INPG_ + k]
               : (k < 160)   ? 0.f
               : Whh[(size_t)row * 512 + (k - 160)];
        WE[(size_t)id * 8 + e] = f2bf(v);
    }
}

// Wfused[r][c] = sum_m Wih_d[r][m] * Wdec1[m][c]   (1536 x 512, fp32)
__global__ void wfused_k(const float* __restrict__ Wih_d, const float* __restrict__ Wdec1,
                         float* __restrict__ Wf) {
    int id = blockIdx.x * 256 + threadIdx.x;
    if (id >= G3_ * H_) return;
    int r = id >> 9, c = id & 511;
    float s = 0.f;
    for (int m = 0; m < 128; ++m)
        s += Wih_d[(size_t)r * 128 + m] * Wdec1[(size_t)m * 512 + c];
    Wf[id] = s;
}

// bfi[r] = bih_d[r] + sum_m Wih_d[r][m] * b_dec1[m]
__global__ void bfi_k(const float* __restrict__ Wih_d, const float* __restrict__ b_dec1,
                      const float* __restrict__ bih_d, float* __restrict__ bfi) {
    int r = blockIdx.x * 256 + threadIdx.x;
    if (r >= G3_) return;
    float s = bih_d[r];
    for (int m = 0; m < 128; ++m)
        s += Wih_d[(size_t)r * 128 + m] * b_dec1[m];
    bfi[r] = s;
}

// decoder weight pack: WD chunks [cb*64 + p*16 + ks][64][8], K=512 each plane.
// fused=1: p0 = Wf_r+Whh_r, p1 = Wf_z+Whh_z, p2 = Wf_n, p3 = Whh_n
// fused=0: p0 = Whh_r, p1 = Whh_z, p2 = 0, p3 = Whh_n
__global__ void pack_wd(const float* __restrict__ Wf, const float* __restrict__ Whh,
                        ushort* __restrict__ WD, int fused) {
    int id = blockIdx.x * 256 + threadIdx.x;   // 131072 total
    int lane = id & 63;
    int rest = id >> 6;
    int ks = rest & 63;
    int cb = rest >> 6;
    if (cb >= 32) return;
    int p = ks >> 4, ksp = ks & 15;
    int n = lane & 15, kb = lane >> 4;
    int j = cb * 16 + n;
    int row = (p == 0) ? j : (p == 1) ? 512 + j : 1024 + j;
    #pragma unroll
    for (int e = 0; e < 8; ++e) {
        int k = ksp * 32 + kb * 8 + e;
        float v;
        if (p <= 1) v = fused ? (Wf[(size_t)row * 512 + k] + Whh[(size_t)row * 512 + k])
                              : Whh[(size_t)row * 512 + k];
        else if (p == 2) v = fused ? Wf[(size_t)row * 512 + k] : 0.f;
        else v = Whh[(size_t)row * 512 + k];
        WD[(size_t)id * 8 + e] = f2bf(v);
    }
}

// Wdec1 MFMA pack for notes GEMM: pk[(nt*16+ks)*64 + lane][8]
__global__ void pack_wdec(const float* __restrict__ Wdec1, ushort* __restrict__ pk) {
    int id = blockIdx.x * 256 + threadIdx.x;   // 8192
    if (id >= 8192) return;
    int lane = id & 63, ch = id >> 6;
    int nt = ch >> 4, ks = ch & 15;
    int n = nt * 16 + (lane & 15);
    int k0 = ks * 32 + (lane >> 4) * 8;
    #pragma unroll
    for (int e = 0; e < 8; ++e)
        pk[(size_t)id * 8 + e] = f2bf(Wdec1[(size_t)n * 512 + k0 + e]);
}

__global__ void zero_init(ushort* __restrict__ hb, int* __restrict__ ef,
                          int* __restrict__ df) {
    int id = blockIdx.x * 256 + threadIdx.x;
    if (id < 4 * 65536) hb[id] = 0;      // [2pp][2dir][128][512]
    if (id < 4096) ef[id] = 0;
    if (id < 2048) df[id] = 0;
}

// note0 -> out[:,0,:] and note0f buffer
__global__ void note0_k2(const float* __restrict__ x, float* __restrict__ out,
                         float* __restrict__ note0f) {
    int id = blockIdx.x * 256 + threadIdx.x;
    if (id >= B_ * IN_) return;
    int b = id >> 7, n = id & 127;
    float v = x[((size_t)b * T_) * INPG_ + n];
    out[((size_t)b * T_) * IN_ + n] = v;
    note0f[(size_t)b * 128 + n] = v;
}

__global__ void cvt_h0(const float* __restrict__ src, ushort* __restrict__ dst) {
    int id = blockIdx.x * 256 + threadIdx.x;
    if (id < B_ * H_) dst[id] = f2bf(src[id]);
}

// ---- W[N][K] fp32 -> tiled bf16 out[KC][N][4] ----
__global__ void tile_w(const float* __restrict__ W, ushort4* __restrict__ out,
                       int N, int K, int KC) {
    int id = blockIdx.x * 256 + threadIdx.x;
    if (id >= KC * N) return;
    int kc = id / N, n = id - kc * N;
    int k = kc * 4;
    ushort4 u;
    u.x = f2bf(k + 0 < K ? W[(size_t)n * K + k + 0] : 0.f);
    u.y = f2bf(k + 1 < K ? W[(size_t)n * K + k + 1] : 0.f);
    u.z = f2bf(k + 2 < K ? W[(size_t)n * K + k + 2] : 0.f);
    u.w = f2bf(k + 3 < K ? W[(size_t)n * K + k + 3] : 0.f);
    out[(size_t)kc * N + n] = u;
}

// =============== persistent encoder ===============
// grid 256 = dir(2) x bt(4) x cb(32); block 256 = 4 waves (gate planes).
// Weights in LDS; fp32 h carry in registers; bf16 h exchanged via hb[pp].
__global__ __launch_bounds__(256) void enc_persist(
    const ushort* __restrict__ xb16, const ushort* __restrict__ WE,
    ushort* __restrict__ hb,            // [2pp][2dir][128][512]
    float* __restrict__ hidden,         // [128][1024]
    const float* __restrict__ bih_f, const float* __restrict__ bhh_f,
    const float* __restrict__ bih_b, const float* __restrict__ bhh_b,
    int* __restrict__ flags)            // 256 x 16 ints (64B spacing)
{
    __shared__ ushort As[32 * 680];      // 43.5 KB
    __shared__ ushort Ws[63 * 512];      // 64.5 KB
    __shared__ float gs[4][512];         // 8 KB
    int bid = blockIdx.x;
    int dir = bid >> 7, bt = (bid >> 5) & 3, cb = bid & 31;
    int b0 = bt * 32;
    int tid = threadIdx.x;
    const float* bih = dir ? bih_b : bih_f;
    const float* bhh = dir ? bhh_b : bhh_f;

    // weight slice -> LDS (once)
    {
        const ushort* src = WE + (size_t)((dir * 32 + cb) * 63) * 512;
        for (int c = tid; c < 4032; c += 256)
            *(uint4*)&Ws[c * 8] = *(const uint4*)&src[c * 8];
    }
    // bias regs (outputs o=tid and o=tid+256 share column j)
    int jj = cb * 16 + (tid & 15);
    float b_r  = bih[jj] + bhh[jj];
    float b_z  = bih[512 + jj] + bhh[512 + jj];
    float b_in = bih[1024 + jj];
    float b_hn = bhh[1024 + jj];
    float hc0 = 0.f, hc1 = 0.f;          // fp32 h carry (block-private columns)

    int lane = tid & 63, wv = tid >> 6;
    int m = lane & 15, kb = lane >> 4;
    int nk  = (wv == 2) ? 5 : (wv == 3) ? 16 : 21;
    int ksb = (wv == 0) ? 0 : (wv == 1) ? 21 : (wv == 2) ? 42 : 47;
    int kcol0 = (wv == 3) ? 160 : 0;
    int ai0 = m * 680 + kcol0 + kb * 8;
    int ai1 = (16 + m) * 680 + kcol0 + kb * 8;
    int bA = tid >> 4, bB = (tid + 256) >> 4;
    int j = jj;

    for (int t = 0; t < T_; ++t) {
        int tt = dir ? (255 - t) : t;
        int pp = t & 1;
        const ushort* hin = hb + (size_t)(pp * 2 + dir) * 65536;
        ushort* hout = hb + (size_t)((pp ^ 1) * 2 + dir) * 65536;
        const ushort* xr = xb16 + (size_t)tt * (B_ * 160);
        // stage A: 84 16B-chunks per row (20 x-part, 64 h-part), 32 rows
        for (int i = 0; i < 11; ++i) {
            int c = tid + i * 256;
            if (c < 2688) {
                int row = c / 84;
                int off = c - row * 84;
                const ushort* s = (off < 20)
                    ? xr + (size_t)(b0 + row) * 160 + off * 8
                    : hin + (size_t)(b0 + row) * 512 + (off - 20) * 8;
                *(uint4*)((char*)As + row * 1360 + off * 16) = *(const uint4*)s;
            }
        }
        __syncthreads();
        f32x4 acc0 = {0.f,0.f,0.f,0.f}, acc1 = {0.f,0.f,0.f,0.f};
        const ushort* Bp = &Ws[ksb * 512 + lane * 8];
        for (int ks = 0; ks < nk; ++ks) {
            bf16x8 bfr = *(const bf16x8*)(Bp + (size_t)ks * 512);
            bf16x8 a0 = *(const bf16x8*)&As[ai0 + ks * 32];
            bf16x8 a1 = *(const bf16x8*)&As[ai1 + ks * 32];
            acc0 = __builtin_amdgcn_mfma_f32_16x16x32_bf16(a0, bfr, acc0, 0, 0, 0);
            acc1 = __builtin_amdgcn_mfma_f32_16x16x32_bf16(a1, bfr, acc1, 0, 0, 0);
        }
        #pragma unroll
        for (int i = 0; i < 4; ++i) {
            gs[wv][(kb * 4 + i) * 16 + m] = acc0[i];
            gs[wv][(16 + kb * 4 + i) * 16 + m] = acc1[i];
        }
        __syncthreads();
        // epilogue (each thread owns outputs tid and tid+256)
        {
            int o0 = tid, o1 = tid + 256;
            float r0 = sigf(gs[0][o0] + b_r);
            float z0 = sigf(gs[1][o0] + b_z);
            float n0 = tanhf(gs[2][o0] + b_in + r0 * (gs[3][o0] + b_hn));
            hc0 = (1.f - z0) * n0 + z0 * hc0;
            float r1 = sigf(gs[0][o1] + b_r);
            float z1 = sigf(gs[1][o1] + b_z);
            float n1 = tanhf(gs[2][o1] + b_in + r1 * (gs[3][o1] + b_hn));
            hc1 = (1.f - z1) * n1 + z1 * hc1;
            hout[(size_t)(b0 + bA) * 512 + j] = f2bf(hc0);
            hout[(size_t)(b0 + bB) * 512 + j] = f2bf(hc1);
            if (t == 255) {
                hidden[(size_t)(b0 + bA) * 1024 + dir * 512 + j] = hc0;
                hidden[(size_t)(b0 + bB) * 1024 + dir * 512 + j] = hc1;
            }
        }
        if (t < 255) {
            __threadfence();                 // release h stores
            __syncthreads();
            if (tid == 0)
                __hip_atomic_store(&flags[bid * 16], t + 1, __ATOMIC_RELAXED,
                                   __HIP_MEMORY_SCOPE_AGENT);
            if (wv == 0) {
                for (;;) {
                    int v0 = __hip_atomic_load(&flags[lane * 16], __ATOMIC_RELAXED, __HIP_MEMORY_SCOPE_AGENT);
                    int v1 = __hip_atomic_load(&flags[(lane + 64) * 16], __ATOMIC_RELAXED, __HIP_MEMORY_SCOPE_AGENT);
                    int v2 = __hip_atomic_load(&flags[(lane + 128) * 16], __ATOMIC_RELAXED, __HIP_MEMORY_SCOPE_AGENT);
                    int v3 = __hip_atomic_load(&flags[(lane + 192) * 16], __ATOMIC_RELAXED, __HIP_MEMORY_SCOPE_AGENT);
                    bool ok = (v0 > t) && (v1 > t) && (v2 > t) && (v3 > t);
                    if (__all(ok)) break;
                    __builtin_amdgcn_s_sleep(2);
                }
            }
            __syncthreads();
            __threadfence();                 // acquire before next h read
        }
    }
}

// =============== persistent decoder ===============
// grid 128 = bt(4) x cb(32); block 256 = 4 waves (planes r,z,gin,ghn; K=512).
__global__ __launch_bounds__(256) void dec_persist(
    const ushort* __restrict__ hdec0, const ushort* __restrict__ WD2,
    const ushort* __restrict__ WD1, ushort* __restrict__ hist,  // [255][128][512]
    const float* __restrict__ h0f, const float* __restrict__ bfi,
    const float* __restrict__ bhh, const float* __restrict__ gi0,
    int* __restrict__ flags)            // 128 x 16 ints
{
    __shared__ ushort As[32 * 520];      // 33.3 KB
    __shared__ ushort Ws[64 * 512];      // 64 KB
    __shared__ float gs[4][512];         // 8 KB
    int bid = blockIdx.x;
    int bt = bid >> 5, cb = bid & 31;
    int b0 = bt * 32, tid = threadIdx.x;
    // fused weights -> LDS (once)
    {
        const ushort* src = WD2 + (size_t)(cb * 64) * 512;
        for (int c = tid; c < 4096; c += 256)
            *(uint4*)&Ws[c * 8] = *(const uint4*)&src[c * 8];
    }
    int jj = cb * 16 + (tid & 15);
    float f_r  = bfi[jj] + bhh[jj];
    float f_z  = bfi[512 + jj] + bhh[512 + jj];
    float f_in = bfi[1024 + jj];
    float f_hn = bhh[1024 + jj];
    float bh_r = bhh[jj], bh_z = bhh[512 + jj];
    int bA = tid >> 4, bB = (tid + 256) >> 4;
    int j = jj;
    float hc0 = h0f[(size_t)(b0 + bA) * 512 + j];
    float hc1 = h0f[(size_t)(b0 + bB) * 512 + j];
    float g0r = gi0[(size_t)(b0 + bA) * G3_ + j];
    float g0z = gi0[(size_t)(b0 + bA) * G3_ + 512 + j];
    float g0n = gi0[(size_t)(b0 + bA) * G3_ + 1024 + j];
    float g1r = gi0[(size_t)(b0 + bB) * G3_ + j];
    float g1z = gi0[(size_t)(b0 + bB) * G3_ + 512 + j];
    float g1n = gi0[(size_t)(b0 + bB) * G3_ + 1024 + j];

    int lane = tid & 63, wv = tid >> 6;
    int m = lane & 15, kb = lane >> 4;
    int ai0 = m * 520 + kb * 8, ai1 = (16 + m) * 520 + kb * 8;
    const ushort* WD1s = WD1 + (size_t)(cb * 64 + wv * 16) * 512 + lane * 8;

    for (int t = 1; t < T_; ++t) {
        const ushort* hsrc = (t == 1) ? hdec0 : hist + (size_t)(t - 2) * 65536;
        #pragma unroll
        for (int i = 0; i < 8; ++i) {
            int c = tid + i * 256;
            int row = c >> 6, off = c & 63;
            *(uint4*)((char*)As + row * 1040 + off * 16) =
                *(const uint4*)(hsrc + (size_t)(b0 + row) * 512 + off * 8);
        }
        __syncthreads();
        f32x4 acc0 = {0.f,0.f,0.f,0.f}, acc1 = {0.f,0.f,0.f,0.f};
        if (t == 1) {
            if (wv != 2) {                 // gin plane zero at t==1
                for (int ks = 0; ks < 16; ++ks) {
                    bf16x8 bfr = *(const bf16x8*)(WD1s + (size_t)ks * 512);
                    bf16x8 a0 = *(const bf16x8*)&As[ai0 + ks * 32];
                    bf16x8 a1 = *(const bf16x8*)&As[ai1 + ks * 32];
                    acc0 = __builtin_amdgcn_mfma_f32_16x16x32_bf16(a0, bfr, acc0, 0, 0, 0);
                    acc1 = __builtin_amdgcn_mfma_f32_16x16x32_bf16(a1, bfr, acc1, 0, 0, 0);
                }
            }
        } else {
            const ushort* Bp = &Ws[(wv * 16) * 512 + lane * 8];
            for (int ks = 0; ks < 16; ++ks) {
                bf16x8 bfr = *(const bf16x8*)(Bp + (size_t)ks * 512);
                bf16x8 a0 = *(const bf16x8*)&As[ai0 + ks * 32];
                bf16x8 a1 = *(const bf16x8*)&As[ai1 + ks * 32];
                acc0 = __builtin_amdgcn_mfma_f32_16x16x32_bf16(a0, bfr, acc0, 0, 0, 0);
                acc1 = __builtin_amdgcn_mfma_f32_16x16x32_bf16(a1, bfr, acc1, 0, 0, 0);
            }
        }
        #pragma unroll
        for (int i = 0; i < 4; ++i) {
            gs[wv][(kb * 4 + i) * 16 + m] = acc0[i];
            gs[wv][(16 + kb * 4 + i) * 16 + m] = acc1[i];
        }
        __syncthreads();
        {
            int o0 = tid, o1 = tid + 256;
            float r0, z0, n0, r1, z1, n1;
            if (t == 1) {
                r0 = sigf(gs[0][o0] + g0r + bh_r);
                z0 = sigf(gs[1][o0] + g0z + bh_z);
                n0 = tanhf(gs[2][o0] + g0n + r0 * (gs[3][o0] + f_hn));
                r1 = sigf(gs[0][o1] + g1r + bh_r);
                z1 = sigf(gs[1][o1] + g1z + bh_z);
                n1 = tanhf(gs[2][o1] + g1n + r1 * (gs[3][o1] + f_hn));
            } else {
                r0 = sigf(gs[0][o0] + f_r);
                z0 = sigf(gs[1][o0] + f_z);
                n0 = tanhf(gs[2][o0] + f_in + r0 * (gs[3][o0] + f_hn));
                r1 = sigf(gs[0][o1] + f_r);
                z1 = sigf(gs[1][o1] + f_z);
                n1 = tanhf(gs[2][o1] + f_in + r1 * (gs[3][o1] + f_hn));
            }
            hc0 = (1.f - z0) * n0 + z0 * hc0;
            hc1 = (1.f - z1) * n1 + z1 * hc1;
            ushort* hdst = hist + (size_t)(t - 1) * 65536;
            hdst[(size_t)(b0 + bA) * 512 + j] = f2bf(hc0);
            hdst[(size_t)(b0 + bB) * 512 + j] = f2bf(hc1);
        }
        if (t < 255) {
            __threadfence();
            __syncthreads();
            if (tid == 0)
                __hip_atomic_store(&flags[bid * 16], t, __ATOMIC_RELAXED,
                                   __HIP_MEMORY_SCOPE_AGENT);
            if (wv == 0) {
                for (;;) {
                    int v0 = __hip_atomic_load(&flags[lane * 16], __ATOMIC_RELAXED, __HIP_MEMORY_SCOPE_AGENT);
                    int v1 = __hip_atomic_load(&flags[(lane + 64) * 16], __ATOMIC_RELAXED, __HIP_MEMORY_SCOPE_AGENT);
                    bool ok = (v0 >= t) && (v1 >= t);
                    if (__all(ok)) break;
                    __builtin_amdgcn_s_sleep(2);
                }
            }
            __syncthreads();
            __threadfence();
        }
    }
}

// =============== notes GEMM (MFMA): hist @ Wdec1.T + b -> out[:,1:,:] ===============
__global__ __launch_bounds__(256) void notes_mfma(
    const ushort* __restrict__ hist, const ushort* __restrict__ pk,
    const float* __restrict__ bd, float* __restrict__ out)
{
    __shared__ ushort hs[32 * 520];
    int m0 = blockIdx.x * 32;           // 1020 blocks x 32 rows
    int tid = threadIdx.x;
    #pragma unroll
    for (int i = 0; i < 8; ++i) {
        int c = tid + i * 256;
        int row = c >> 6, off = c & 63;
        *(uint4*)((char*)hs + row * 1040 + off * 16) =
            *(const uint4*)(hist + (size_t)(m0 + row) * 512 + off * 8);
    }
    __syncthreads();
    int lane = tid & 63, wv = tid >> 6;
    int m = lane & 15, kb = lane >> 4;
    int nt0 = wv * 2;
    f32x4 acc00 = {0.f,0.f,0.f,0.f}, acc01 = {0.f,0.f,0.f,0.f};
    f32x4 acc10 = {0.f,0.f,0.f,0.f}, acc11 = {0.f,0.f,0.f,0.f};
    for (int ks = 0; ks < 16; ++ks) {
        bf16x8 a0 = *(const bf16x8*)&hs[m * 520 + ks * 32 + kb * 8];
        bf16x8 a1 = *(const bf16x8*)&hs[(16 + m) * 520 + ks * 32 + kb * 8];
        bf16x8 bf0 = *(const bf16x8*)&pk[(size_t)((nt0 * 16 + ks) * 64 + lane) * 8];
        bf16x8 bf1 = *(const bf16x8*)&pk[(size_t)(((nt0 + 1) * 16 + ks) * 64 + lane) * 8];
        acc00 = __builtin_amdgcn_mfma_f32_16x16x32_bf16(a0, bf0, acc00, 0, 0, 0);
        acc01 = __builtin_amdgcn_mfma_f32_16x16x32_bf16(a0, bf1, acc01, 0, 0, 0);
        acc10 = __builtin_amdgcn_mfma_f32_16x16x32_bf16(a1, bf0, acc10, 0, 0, 0);
        acc11 = __builtin_amdgcn_mfma_f32_16x16x32_bf16(a1, bf1, acc11, 0, 0, 0);
    }
    int n0 = nt0 * 16 + (lane & 15), n1 = (nt0 + 1) * 16 + (lane & 15);
    #pragma unroll
    for (int i = 0; i < 4; ++i) {
        int r0 = m0 + kb * 4 + i;
        int r1 = r0 + 16;
        int t0 = r0 >> 7, b0r = r0 & 127;
        int t1 = r1 >> 7, b1r = r1 & 127;
        out[((size_t)b0r * T_ + (t0 + 1)) * IN_ + n0] = acc00[i] + bd[n0];
        out[((size_t)b0r * T_ + (t0 + 1)) * IN_ + n1] = acc01[i] + bd[n1];
        out[((size_t)b1r * T_ + (t1 + 1)) * IN_ + n0] = acc10[i] + bd[n0];
        out[((size_t)b1r * T_ + (t1 + 1)) * IN_ + n1] = acc11[i] + bd[n1];
    }
}

// =============== MLP GEMM (fp32 A, bf16 tiled W) ===============
__global__ __launch_bounds__(256) void gemm_t4(
    const float* __restrict__ A, const ushort4* __restrict__ Wt,
    const float* __restrict__ bias, float* __restrict__ C,
    int M, int N, int K, int act)
{
    int nb = blockIdx.x, mb = blockIdx.y;
    int tid = threadIdx.x;
    int n = nb * 64 + (tid & 63);
    int mq = tid >> 6;
    int m0 = mb * 32;
    __shared__ float Asm[32][36];
    float acc[8];
    #pragma unroll
    for (int i = 0; i < 8; ++i) acc[i] = 0.f;
    for (int k0 = 0; k0 < K; k0 += 32) {
        int r = tid >> 3, c = (tid & 7) << 2;
        float4 v = *(const float4*)&A[(size_t)(m0 + r) * K + k0 + c];
        Asm[r][c] = v.x; Asm[r][c+1] = v.y; Asm[r][c+2] = v.z; Asm[r][c+3] = v.w;
        __syncthreads();
        #pragma unroll
        for (int kc = 0; kc < 8; ++kc) {
            float w0 = 0.f, w1 = 0.f, w2 = 0.f, w3 = 0.f;
            if (n < N) {
                ushort4 u = Wt[(size_t)((k0 >> 2) + kc) * N + n];
                w0 = bf2f(u.x); w1 = bf2f(u.y); w2 = bf2f(u.z); w3 = bf2f(u.w);
            }
            #pragma unroll
            for (int i = 0; i < 8; ++i) {
                int mm = mq * 8 + i;
                acc[i] += Asm[mm][kc*4+0]*w0 + Asm[mm][kc*4+1]*w1
                        + Asm[mm][kc*4+2]*w2 + Asm[mm][kc*4+3]*w3;
            }
        }
        __syncthreads();
    }
    if (n < N) {
        #pragma unroll
        for (int i = 0; i < 8; ++i) {
            int mm = m0 + mq * 8 + i;
            float v = acc[i] + bias[n];
            if (act == 1) v = (v >= 0.f) ? v : 0.01f * v;
            C[(size_t)mm * N + n] = v;
        }
    }
}

__global__ void z_k(const float* __restrict__ out, const float* __restrict__ eps,
                    const float* __restrict__ genre, float* __restrict__ zc) {
    int id = blockIdx.x * 256 + threadIdx.x;
    if (id >= B_ * L_) return;
    int b = id >> 8, c = id & 255;
    float v;
    if (c < LG_) {
        float mu = out[MU_OFF + (size_t)b * LG_ + c];
        float lv = out[LV_OFF + (size_t)b * LG_ + c];
        v = mu + expf(0.5f * lv) * eps[(size_t)b * LG_ + c];
    } else {
        v = genre[(size_t)b * G_ + (c - LG_)];
    }
    zc[id] = v;
}

// =============== host ===============
extern "C" void kernel_launch(void* const* d_in, const int* in_sizes, int n_in,
                              void* d_out, int out_size, void* d_ws, size_t ws_size,
                              hipStream_t stream) {
    (void)in_sizes; (void)n_in; (void)out_size; (void)ws_size;
    const float* x      = (const float*)d_in[0];
    const float* genre  = (const float*)d_in[1];
    const float* eps    = (const float*)d_in[2];
    const float* Wih_e  = (const float*)d_in[3];
    const float* Whh_e  = (const float*)d_in[4];
    const float* bih_e  = (const float*)d_in[5];
    const float* bhh_e  = (const float*)d_in[6];
    const float* Wih_be = (const float*)d_in[7];
    const float* Whh_be = (const float*)d_in[8];
    const float* bih_be = (const float*)d_in[9];
    const float* bhh_be = (const float*)d_in[10];
    const float* Wih_d  = (const float*)d_in[11];
    const float* Whh_d  = (const float*)d_in[12];
    const float* bih_d  = (const float*)d_in[13];
    const float* bhh_d  = (const float*)d_in[14];
    const float* W_mu0  = (const float*)d_in[15];
    const float* b_mu0  = (const float*)d_in[16];
    const float* W_mu1  = (const float*)d_in[17];
    const float* b_mu1  = (const float*)d_in[18];
    const float* W_lv0  = (const float*)d_in[19];
    const float* b_lv0  = (const float*)d_in[20];
    const float* W_lv1  = (const float*)d_in[21];
    const float* b_lv1  = (const float*)d_in[22];
    const float* W_lat0 = (const float*)d_in[23];
    const float* b_lat0 = (const float*)d_in[24];
    const float* W_lat1 = (const float*)d_in[25];
    const float* b_lat1 = (const float*)d_in[26];
    const float* W_dec1 = (const float*)d_in[27];
    const float* b_dec1 = (const float*)d_in[28];
    float* out = (float*)d_out;

    char* ws = (char*)d_ws;
    size_t off = 0;
    auto alloc = [&](size_t bytes) -> char* {
        char* p = ws + off;
        off = (off + bytes + 255) & ~(size_t)255;
        return p;
    };
    ushort* xb16  = (ushort*)alloc((size_t)T_ * B_ * 160 * 2);
    ushort* WE    = (ushort*)alloc((size_t)2 * 32 * 63 * 512 * 2);
    ushort* WD2   = (ushort*)alloc((size_t)32 * 64 * 512 * 2);
    ushort* WD1   = (ushort*)alloc((size_t)32 * 64 * 512 * 2);
    float*  Wf    = (float*)alloc((size_t)G3_ * H_ * 4);
    float*  bfi   = (float*)alloc(G3_ * 4);
    ushort* hb_e  = (ushort*)alloc((size_t)4 * 65536 * 2);
    ushort* hist  = (ushort*)alloc((size_t)255 * 65536 * 2);
    ushort* hdec0 = (ushort*)alloc((size_t)65536 * 2);
    ushort* pkdec = (ushort*)alloc((size_t)8192 * 8 * 2);
    int*    eflag = (int*)alloc((size_t)4096 * 4);
    int*    dflag = (int*)alloc((size_t)2048 * 4);
    float*  note0f= (float*)alloc((size_t)B_ * 128 * 4);
    float*  gi0   = (float*)alloc((size_t)B_ * G3_ * 4);
    float*  hidden= (float*)alloc((size_t)B_ * E_ * 4);
    float*  t0buf = (float*)alloc((size_t)B_ * E_ * 4);
    float*  t1buf = (float*)alloc((size_t)B_ * E_ * 4);
    float*  zcbuf = (float*)alloc((size_t)B_ * L_ * 4);
    float*  t2buf = (float*)alloc((size_t)B_ * L_ * 4);
    float*  t3buf = (float*)alloc((size_t)B_ * H_ * 4);

    ushort4* T_Wmu0  = (ushort4*)alloc((size_t)256 * E_ * 8);
    ushort4* T_Wmu1  = (ushort4*)alloc((size_t)256 * LG_ * 8);
    ushort4* T_Wlv0  = (ushort4*)alloc((size_t)256 * E_ * 8);
    ushort4* T_Wlv1  = (ushort4*)alloc((size_t)256 * LG_ * 8);
    ushort4* T_Wlat0 = (ushort4*)alloc((size_t)64 * L_ * 8);
    ushort4* T_Wlat1 = (ushort4*)alloc((size_t)64 * H_ * 8);
    ushort4* T_Wihd  = (ushort4*)alloc((size_t)32 * G3_ * 8);

    // ---- prep ----
    xpad_k<<<(T_ * B_ * 160 + 255) / 256, 256, 0, stream>>>(x, xb16);
    pack_we<<<1008, 256, 0, stream>>>(Wih_e, Whh_e, Wih_be, Whh_be, WE);
    wfused_k<<<(G3_ * H_ + 255) / 256, 256, 0, stream>>>(Wih_d, W_dec1, Wf);
    bfi_k<<<6, 256, 0, stream>>>(Wih_d, b_dec1, bih_d, bfi);
    pack_wd<<<512, 256, 0, stream>>>(Wf, Whh_d, WD2, 1);
    pack_wd<<<512, 256, 0, stream>>>(Wf, Whh_d, WD1, 0);
    pack_wdec<<<32, 256, 0, stream>>>(W_dec1, pkdec);
    zero_init<<<1024, 256, 0, stream>>>(hb_e, eflag, dflag);
    note0_k2<<<(B_ * IN_ + 255) / 256, 256, 0, stream>>>(x, out, note0f);

    auto tile = [&](const float* W, ushort4* dst, int N, int K) {
        int KC = (K + 3) / 4;
        tile_w<<<(KC * N + 255) / 256, 256, 0, stream>>>(W, dst, N, K, KC);
    };
    tile(W_mu0,  T_Wmu0,  E_,  E_);
    tile(W_mu1,  T_Wmu1,  LG_, E_);
    tile(W_lv0,  T_Wlv0,  E_,  E_);
    tile(W_lv1,  T_Wlv1,  LG_, E_);
    tile(W_lat0, T_Wlat0, L_,  L_);
    tile(W_lat1, T_Wlat1, H_,  L_);
    tile(Wih_d,  T_Wihd,  G3_, IN_);

    // ---- persistent bidirectional encoder (256 steps internally) ----
    enc_persist<<<256, 256, 0, stream>>>(xb16, WE, hb_e, hidden,
                                         bih_e, bhh_e, bih_be, bhh_be, eflag);

    // ---- MLP bottleneck ----
    {
        dim3 g1(16, 4), g2(4, 4), g3(4, 4), g4(8, 4), g5(24, 4);
        gemm_t4<<<g1, 256, 0, stream>>>(hidden, T_Wmu0, b_mu0, t0buf, B_, E_, E_, 1);
        gemm_t4<<<g2, 256, 0, stream>>>(t0buf, T_Wmu1, b_mu1, out + MU_OFF, B_, LG_, E_, 0);
        gemm_t4<<<g1, 256, 0, stream>>>(hidden, T_Wlv0, b_lv0, t1buf, B_, E_, E_, 1);
        gemm_t4<<<g2, 256, 0, stream>>>(t1buf, T_Wlv1, b_lv1, out + LV_OFF, B_, LG_, E_, 0);
        z_k<<<(B_ * L_ + 255) / 256, 256, 0, stream>>>(out, eps, genre, zcbuf);
        gemm_t4<<<g3, 256, 0, stream>>>(zcbuf, T_Wlat0, b_lat0, t2buf, B_, L_, L_, 1);
        gemm_t4<<<g4, 256, 0, stream>>>(t2buf, T_Wlat1, b_lat1, t3buf, B_, H_, L_, 0);
        gemm_t4<<<g5, 256, 0, stream>>>(note0f, T_Wihd, bih_d, gi0, B_, G3_, IN_, 0);
    }
    cvt_h0<<<(B_ * H_ + 255) / 256, 256, 0, stream>>>(t3buf, hdec0);

    // ---- persistent decoder (255 steps internally) ----
    dec_persist<<<128, 256, 0, stream>>>(hdec0, WD2, WD1, hist, t3buf,
                                         bfi, bhh_d, gi0, dflag);

    // ---- all notes (MFMA GEMM) ----
    notes_mfma<<<1020, 256, 0, stream>>>(hist, pkdec, b_dec1, out);
}

// Round 4
// 2303.127 us; speedup vs baseline: 7.2592x; 7.2592x over previous
//
#include <hip/hip_runtime.h>

#define B_ 128
#define T_ 256
#define IN_ 128
#define G_ 5
#define H_ 512
#define G3_ 1536
#define E_ 1024
#define L_ 256
#define LG_ 251
#define INPG_ 133

#define MU_OFF (B_*T_*IN_)            /* 4194304 */
#define LV_OFF (MU_OFF + B_*LG_)      /* 4226432 */

typedef __attribute__((ext_vector_type(8))) short bf16x8;
typedef __attribute__((ext_vector_type(4))) float f32x4;
typedef unsigned long long u64;

__device__ __forceinline__ float bf2f(unsigned short s) {
    return __uint_as_float(((unsigned)s) << 16);
}
__device__ __forceinline__ unsigned short f2bf(float f) {
    unsigned x = __float_as_uint(f);
    unsigned r = (x + 0x7fffu + ((x >> 16) & 1u)) >> 16;
    return (unsigned short)r;
}
__device__ __forceinline__ float sigf(float v) {
    return 1.f / (1.f + __expf(-v));
}
// ---- agent-scope (cross-XCD coherent, no cache flush) data/flag ops ----
__device__ __forceinline__ int ld_flag(const int* p) {
    return __hip_atomic_load(p, __ATOMIC_RELAXED, __HIP_MEMORY_SCOPE_AGENT);
}
__device__ __forceinline__ void st_flag(int* p, int v) {
    __hip_atomic_store(p, v, __ATOMIC_RELAXED, __HIP_MEMORY_SCOPE_AGENT);
}
__device__ __forceinline__ u64 ld_h64(const void* p) {
    return __hip_atomic_load((const u64*)p, __ATOMIC_RELAXED, __HIP_MEMORY_SCOPE_AGENT);
}
__device__ __forceinline__ void st_h32(void* p, unsigned v) {
    __hip_atomic_store((unsigned*)p, v, __ATOMIC_RELAXED, __HIP_MEMORY_SCOPE_AGENT);
}

// =============== prep kernels ===============

__global__ void xpad_k(const float* __restrict__ x, ushort* __restrict__ xb) {
    int id = blockIdx.x * 256 + threadIdx.x;
    if (id >= T_ * B_ * 160) return;
    int t = id / (B_ * 160);
    int rem = id - t * (B_ * 160);
    int b = rem / 160, c = rem - b * 160;
    float v = (c < INPG_) ? x[((size_t)b * T_ + t) * INPG_ + c] : 0.f;
    xb[id] = f2bf(v);
}

// encoder weight pack: WE chunks [(dir*32+cb)*63 + ks][64 lanes][8 bf16]
__global__ void pack_we(const float* __restrict__ Wih_f, const float* __restrict__ Whh_f,
                        const float* __restrict__ Wih_b, const float* __restrict__ Whh_b,
                        ushort* __restrict__ WE) {
    int id = blockIdx.x * 256 + threadIdx.x;
    int lane = id & 63;
    int rest = id >> 6;
    int ks = rest % 63;
    int cb = (rest / 63) & 31;
    int dir = rest / (63 * 32);
    if (dir >= 2) return;
    const float* Wih = dir ? Wih_b : Wih_f;
    const float* Whh = dir ? Whh_b : Whh_f;
    int n = lane & 15, kb = lane >> 4;
    int p, ksp;
    if (ks < 21)      { p = 0; ksp = ks; }
    else if (ks < 42) { p = 1; ksp = ks - 21; }
    else if (ks < 47) { p = 2; ksp = ks - 42; }
    else              { p = 3; ksp = ks - 47; }
    int j = cb * 16 + n;
    int row = (p == 0) ? j : (p == 1) ? 512 + j : 1024 + j;
    #pragma unroll
    for (int e = 0; e < 8; ++e) {
        int k = ksp * 32 + kb * 8 + e;
        float v;
        if (p == 3)      v = Whh[(size_t)row * 512 + k];
        else if (p == 2) v = (k < INPG_) ? Wih[(size_t)row * INPG_ + k] : 0.f;
        else v = (k < INPG_) ? Wih[(size_t)row * INPG_ + k]
               : (k < 160)   ? 0.f
               : Whh[(size_t)row * 512 + (k - 160)];
        WE[(size_t)id * 8 + e] = f2bf(v);
    }
}

__global__ void wfused_k(const float* __restrict__ Wih_d, const float* __restrict__ Wdec1,
                         float* __restrict__ Wf) {
    int id = blockIdx.x * 256 + threadIdx.x;
    if (id >= G3_ * H_) return;
    int r = id >> 9, c = id & 511;
    float s = 0.f;
    for (int m = 0; m < 128; ++m)
        s += Wih_d[(size_t)r * 128 + m] * Wdec1[(size_t)m * 512 + c];
    Wf[id] = s;
}

__global__ void bfi_k(const float* __restrict__ Wih_d, const float* __restrict__ b_dec1,
                      const float* __restrict__ bih_d, float* __restrict__ bfi) {
    int r = blockIdx.x * 256 + threadIdx.x;
    if (r >= G3_) return;
    float s = bih_d[r];
    for (int m = 0; m < 128; ++m)
        s += Wih_d[(size_t)r * 128 + m] * b_dec1[m];
    bfi[r] = s;
}

__global__ void pack_wd(const float* __restrict__ Wf, const float* __restrict__ Whh,
                        ushort* __restrict__ WD, int fused) {
    int id = blockIdx.x * 256 + threadIdx.x;
    int lane = id & 63;
    int rest = id >> 6;
    int ks = rest & 63;
    int cb = rest >> 6;
    if (cb >= 32) return;
    int p = ks >> 4, ksp = ks & 15;
    int n = lane & 15, kb = lane >> 4;
    int j = cb * 16 + n;
    int row = (p == 0) ? j : (p == 1) ? 512 + j : 1024 + j;
    #pragma unroll
    for (int e = 0; e < 8; ++e) {
        int k = ksp * 32 + kb * 8 + e;
        float v;
        if (p <= 1) v = fused ? (Wf[(size_t)row * 512 + k] + Whh[(size_t)row * 512 + k])
                              : Whh[(size_t)row * 512 + k];
        else if (p == 2) v = fused ? Wf[(size_t)row * 512 + k] : 0.f;
        else v = Whh[(size_t)row * 512 + k];
        WD[(size_t)id * 8 + e] = f2bf(v);
    }
}

__global__ void pack_wdec(const float* __restrict__ Wdec1, ushort* __restrict__ pk) {
    int id = blockIdx.x * 256 + threadIdx.x;
    if (id >= 8192) return;
    int lane = id & 63, ch = id >> 6;
    int nt = ch >> 4, ks = ch & 15;
    int n = nt * 16 + (lane & 15);
    int k0 = ks * 32 + (lane >> 4) * 8;
    #pragma unroll
    for (int e = 0; e < 8; ++e)
        pk[(size_t)id * 8 + e] = f2bf(Wdec1[(size_t)n * 512 + k0 + e]);
}

__global__ void zero_init(ushort* __restrict__ hb, int* __restrict__ ef,
                          int* __restrict__ df) {
    int id = blockIdx.x * 256 + threadIdx.x;
    if (id < 4 * 65536) hb[id] = 0;
    if (id < 4096) ef[id] = 0;
    if (id < 2048) df[id] = 0;
}

__global__ void note0_k2(const float* __restrict__ x, float* __restrict__ out,
                         float* __restrict__ note0f) {
    int id = blockIdx.x * 256 + threadIdx.x;
    if (id >= B_ * IN_) return;
    int b = id >> 7, n = id & 127;
    float v = x[((size_t)b * T_) * INPG_ + n];
    out[((size_t)b * T_) * IN_ + n] = v;
    note0f[(size_t)b * 128 + n] = v;
}

__global__ void cvt_h0(const float* __restrict__ src, ushort* __restrict__ dst) {
    int id = blockIdx.x * 256 + threadIdx.x;
    if (id < B_ * H_) dst[id] = f2bf(src[id]);
}

__global__ void tile_w(const float* __restrict__ W, ushort4* __restrict__ out,
                       int N, int K, int KC) {
    int id = blockIdx.x * 256 + threadIdx.x;
    if (id >= KC * N) return;
    int kc = id / N, n = id - kc * N;
    int k = kc * 4;
    ushort4 u;
    u.x = f2bf(k + 0 < K ? W[(size_t)n * K + k + 0] : 0.f);
    u.y = f2bf(k + 1 < K ? W[(size_t)n * K + k + 1] : 0.f);
    u.z = f2bf(k + 2 < K ? W[(size_t)n * K + k + 2] : 0.f);
    u.w = f2bf(k + 3 < K ? W[(size_t)n * K + k + 3] : 0.f);
    out[(size_t)kc * N + n] = u;
}

// =============== persistent encoder ===============
// grid 256 = dir(2) x bt(4) x cb(32); block 256 = 4 waves (gate planes).
// No fences: h exchanged via agent-scope write-through atomics; group barrier of 32.
__global__ __launch_bounds__(256) void enc_persist(
    const ushort* __restrict__ xb16, const ushort* __restrict__ WE,
    ushort* __restrict__ hb,            // [2pp][2dir][128][512]
    float* __restrict__ hidden,         // [128][1024]
    const float* __restrict__ bih_f, const float* __restrict__ bhh_f,
    const float* __restrict__ bih_b, const float* __restrict__ bhh_b,
    int* __restrict__ flags)            // 256 x 16 ints (64B spacing)
{
    __shared__ ushort As[32 * 680];      // 43.5 KB
    __shared__ ushort Ws[63 * 512];      // 64.5 KB
    __shared__ float gs[4][512];         // 8 KB
    int bid = blockIdx.x;
    int dir = bid >> 7, bt = (bid >> 5) & 3, cb = bid & 31;
    int b0 = bt * 32;
    int tid = threadIdx.x;
    const float* bih = dir ? bih_b : bih_f;
    const float* bhh = dir ? bhh_b : bhh_f;

    // weight slice -> LDS (once)
    {
        const ushort* src = WE + (size_t)((dir * 32 + cb) * 63) * 512;
        for (int c = tid; c < 4032; c += 256)
            *(uint4*)&Ws[c * 8] = *(const uint4*)&src[c * 8];
    }
    // thread owns (row bA, cols j0,j1) of the h tile
    int bA = tid >> 3;
    int j0 = cb * 16 + 2 * (tid & 7), j1 = j0 + 1;
    float b_r0 = bih[j0] + bhh[j0],        b_r1 = bih[j1] + bhh[j1];
    float b_z0 = bih[512 + j0] + bhh[512 + j0], b_z1 = bih[512 + j1] + bhh[512 + j1];
    float b_in0 = bih[1024 + j0],          b_in1 = bih[1024 + j1];
    float b_hn0 = bhh[1024 + j0],          b_hn1 = bhh[1024 + j1];
    float hc0 = 0.f, hc1 = 0.f;

    int lane = tid & 63, wv = tid >> 6;
    int m = lane & 15, kb = lane >> 4;
    int nk  = (wv == 2) ? 5 : (wv == 3) ? 16 : 21;
    int ksb = (wv == 0) ? 0 : (wv == 1) ? 21 : (wv == 2) ? 42 : 47;
    int kcol0 = (wv == 3) ? 160 : 0;
    int ai0 = m * 680 + kcol0 + kb * 8;
    int ai1 = (16 + m) * 680 + kcol0 + kb * 8;
    const int* fpoll = &flags[((bid & ~31) + (lane & 31)) * 16];

    // stage x-tile for t (normal cached loads; LDS row stride 1360B = 85*16)
    auto stage_x = [&](int t2) {
        int tt2 = dir ? (255 - t2) : t2;
        const ushort* xr2 = xb16 + (size_t)tt2 * (B_ * 160);
        #pragma unroll
        for (int i = 0; i < 3; ++i) {
            int c = tid + i * 256;
            if (c < 640) {
                int row = c / 20, off = c - row * 20;
                *(uint4*)((char*)As + row * 1360 + off * 16) =
                    *(const uint4*)(xr2 + (size_t)(b0 + row) * 160 + off * 8);
            }
        }
    };
    stage_x(0);

    for (int t = 0; t < T_; ++t) {
        int pp = t & 1;
        const ushort* hin = hb + (size_t)(pp * 2 + dir) * 65536;
        ushort* hout = hb + (size_t)((pp ^ 1) * 2 + dir) * 65536;
        // wait for group to finish step t-1 (h for step t available)
        if (t > 0) {
            if (wv == 0)
                while (!__all(ld_flag(fpoll) >= t)) __builtin_amdgcn_s_sleep(1);
            __syncthreads();
        }
        // stage h-part via agent-scope u64 loads (batched: loads then LDS stores)
        {
            u64 vb[16];
            #pragma unroll
            for (int i = 0; i < 16; ++i) {
                int c = tid + i * 256;
                int row = c >> 7, off = c & 127;
                vb[i] = ld_h64(hin + (size_t)(b0 + row) * 512 + off * 4);
            }
            #pragma unroll
            for (int i = 0; i < 16; ++i) {
                int c = tid + i * 256;
                int row = c >> 7, off = c & 127;
                *(u64*)((char*)As + row * 1360 + 320 + off * 8) = vb[i];
            }
        }
        __syncthreads();
        f32x4 acc0 = {0.f,0.f,0.f,0.f}, acc1 = {0.f,0.f,0.f,0.f};
        const ushort* Bp = &Ws[ksb * 512 + lane * 8];
        for (int ks = 0; ks < nk; ++ks) {
            bf16x8 bfr = *(const bf16x8*)(Bp + (size_t)ks * 512);
            bf16x8 a0 = *(const bf16x8*)&As[ai0 + ks * 32];
            bf16x8 a1 = *(const bf16x8*)&As[ai1 + ks * 32];
            acc0 = __builtin_amdgcn_mfma_f32_16x16x32_bf16(a0, bfr, acc0, 0, 0, 0);
            acc1 = __builtin_amdgcn_mfma_f32_16x16x32_bf16(a1, bfr, acc1, 0, 0, 0);
        }
        #pragma unroll
        for (int i = 0; i < 4; ++i) {
            gs[wv][(kb * 4 + i) * 16 + m] = acc0[i];
            gs[wv][(16 + kb * 4 + i) * 16 + m] = acc1[i];
        }
        __syncthreads();
        // epilogue: outputs o0=2*tid, o1=2*tid+1 -> (row bA, cols j0,j1)
        {
            int o0 = 2 * tid, o1 = o0 + 1;
            float r0 = sigf(gs[0][o0] + b_r0);
            float z0 = sigf(gs[1][o0] + b_z0);
            float n0 = tanhf(gs[2][o0] + b_in0 + r0 * (gs[3][o0] + b_hn0));
            hc0 = (1.f - z0) * n0 + z0 * hc0;
            float r1 = sigf(gs[0][o1] + b_r1);
            float z1 = sigf(gs[1][o1] + b_z1);
            float n1 = tanhf(gs[2][o1] + b_in1 + r1 * (gs[3][o1] + b_hn1));
            hc1 = (1.f - z1) * n1 + z1 * hc1;
            unsigned pkd = (unsigned)f2bf(hc0) | ((unsigned)f2bf(hc1) << 16);
            st_h32((char*)hout + ((size_t)(b0 + bA) * 512 + j0) * 2, pkd);
            if (t == 255) {
                float2 hv = {hc0, hc1};
                *(float2*)&hidden[(size_t)(b0 + bA) * 1024 + dir * 512 + j0] = hv;
            }
        }
        __syncthreads();   // drains all waves' stores (vmcnt0) before flag
        if (t < 255) {
            if (tid == 0) st_flag(&flags[bid * 16], t + 1);
            stage_x(t + 1);   // overlap next x staging with group catch-up
        }
    }
}

// =============== persistent decoder ===============
// grid 128 = bt(4) x cb(32); block 256 = 4 waves (planes r,z,gin,ghn; K=512).
__global__ __launch_bounds__(256) void dec_persist(
    const ushort* __restrict__ hdec0, const ushort* __restrict__ WD2,
    const ushort* __restrict__ WD1, ushort* __restrict__ hist,  // [255][128][512]
    const float* __restrict__ h0f, const float* __restrict__ bfi,
    const float* __restrict__ bhh, const float* __restrict__ gi0,
    int* __restrict__ flags)            // 128 x 16 ints
{
    __shared__ ushort As[32 * 520];      // 33.3 KB
    __shared__ ushort Ws[64 * 512];      // 64 KB
    __shared__ float gs[4][512];         // 8 KB
    int bid = blockIdx.x;
    int bt = bid >> 5, cb = bid & 31;
    int b0 = bt * 32, tid = threadIdx.x;
    {
        const ushort* src = WD2 + (size_t)(cb * 64) * 512;
        for (int c = tid; c < 4096; c += 256)
            *(uint4*)&Ws[c * 8] = *(const uint4*)&src[c * 8];
    }
    int bA = tid >> 3;
    int j0 = cb * 16 + 2 * (tid & 7), j1 = j0 + 1;
    float f_r0 = bfi[j0] + bhh[j0],             f_r1 = bfi[j1] + bhh[j1];
    float f_z0 = bfi[512 + j0] + bhh[512 + j0], f_z1 = bfi[512 + j1] + bhh[512 + j1];
    float f_in0 = bfi[1024 + j0],               f_in1 = bfi[1024 + j1];
    float f_hn0 = bhh[1024 + j0],               f_hn1 = bhh[1024 + j1];
    float bh_r0 = bhh[j0], bh_r1 = bhh[j1];
    float bh_z0 = bhh[512 + j0], bh_z1 = bhh[512 + j1];
    float hc0 = h0f[(size_t)(b0 + bA) * 512 + j0];
    float hc1 = h0f[(size_t)(b0 + bA) * 512 + j1];
    float g0r = gi0[(size_t)(b0 + bA) * G3_ + j0];
    float g1r = gi0[(size_t)(b0 + bA) * G3_ + j1];
    float g0z = gi0[(size_t)(b0 + bA) * G3_ + 512 + j0];
    float g1z = gi0[(size_t)(b0 + bA) * G3_ + 512 + j1];
    float g0n = gi0[(size_t)(b0 + bA) * G3_ + 1024 + j0];
    float g1n = gi0[(size_t)(b0 + bA) * G3_ + 1024 + j1];

    int lane = tid & 63, wv = tid >> 6;
    int m = lane & 15, kb = lane >> 4;
    int ai0 = m * 520 + kb * 8, ai1 = (16 + m) * 520 + kb * 8;
    const ushort* WD1s = WD1 + (size_t)(cb * 64 + wv * 16) * 512 + lane * 8;
    const int* fpoll = &flags[((bid & ~31) + (lane & 31)) * 16];

    for (int t = 1; t < T_; ++t) {
        if (t >= 2) {
            if (wv == 0)
                while (!__all(ld_flag(fpoll) >= t - 1)) __builtin_amdgcn_s_sleep(1);
            __syncthreads();
        }
        const ushort* hsrc = (t == 1) ? hdec0 : hist + (size_t)(t - 2) * 65536;
        {
            u64 vb[16];
            #pragma unroll
            for (int i = 0; i < 16; ++i) {
                int c = tid + i * 256;
                int row = c >> 7, off = c & 127;
                vb[i] = ld_h64(hsrc + (size_t)(b0 + row) * 512 + off * 4);
            }
            #pragma unroll
            for (int i = 0; i < 16; ++i) {
                int c = tid + i * 256;
                int row = c >> 7, off = c & 127;
                *(u64*)((char*)As + row * 1040 + off * 8) = vb[i];
            }
        }
        __syncthreads();
        f32x4 acc0 = {0.f,0.f,0.f,0.f}, acc1 = {0.f,0.f,0.f,0.f};
        if (t == 1) {
            if (wv != 2) {
                for (int ks = 0; ks < 16; ++ks) {
                    bf16x8 bfr = *(const bf16x8*)(WD1s + (size_t)ks * 512);
                    bf16x8 a0 = *(const bf16x8*)&As[ai0 + ks * 32];
                    bf16x8 a1 = *(const bf16x8*)&As[ai1 + ks * 32];
                    acc0 = __builtin_amdgcn_mfma_f32_16x16x32_bf16(a0, bfr, acc0, 0, 0, 0);
                    acc1 = __builtin_amdgcn_mfma_f32_16x16x32_bf16(a1, bfr, acc1, 0, 0, 0);
                }
            }
        } else {
            const ushort* Bp = &Ws[(wv * 16) * 512 + lane * 8];
            for (int ks = 0; ks < 16; ++ks) {
                bf16x8 bfr = *(const bf16x8*)(Bp + (size_t)ks * 512);
                bf16x8 a0 = *(const bf16x8*)&As[ai0 + ks * 32];
                bf16x8 a1 = *(const bf16x8*)&As[ai1 + ks * 32];
                acc0 = __builtin_amdgcn_mfma_f32_16x16x32_bf16(a0, bfr, acc0, 0, 0, 0);
                acc1 = __builtin_amdgcn_mfma_f32_16x16x32_bf16(a1, bfr, acc1, 0, 0, 0);
            }
        }
        #pragma unroll
        for (int i = 0; i < 4; ++i) {
            gs[wv][(kb * 4 + i) * 16 + m] = acc0[i];
            gs[wv][(16 + kb * 4 + i) * 16 + m] = acc1[i];
        }
        __syncthreads();
        {
            int o0 = 2 * tid, o1 = o0 + 1;
            float r0, z0, n0, r1, z1, n1;
            if (t == 1) {
                r0 = sigf(gs[0][o0] + g0r + bh_r0);
                z0 = sigf(gs[1][o0] + g0z + bh_z0);
                n0 = tanhf(gs[2][o0] + g0n + r0 * (gs[3][o0] + f_hn0));
                r1 = sigf(gs[0][o1] + g1r + bh_r1);
                z1 = sigf(gs[1][o1] + g1z + bh_z1);
                n1 = tanhf(gs[2][o1] + g1n + r1 * (gs[3][o1] + f_hn1));
            } else {
                r0 = sigf(gs[0][o0] + f_r0);
                z0 = sigf(gs[1][o0] + f_z0);
                n0 = tanhf(gs[2][o0] + f_in0 + r0 * (gs[3][o0] + f_hn0));
                r1 = sigf(gs[0][o1] + f_r1);
                z1 = sigf(gs[1][o1] + f_z1);
                n1 = tanhf(gs[2][o1] + f_in1 + r1 * (gs[3][o1] + f_hn1));
            }
            hc0 = (1.f - z0) * n0 + z0 * hc0;
            hc1 = (1.f - z1) * n1 + z1 * hc1;
            unsigned pkd = (unsigned)f2bf(hc0) | ((unsigned)f2bf(hc1) << 16);
            st_h32((char*)(hist + (size_t)(t - 1) * 65536) +
                   ((size_t)(b0 + bA) * 512 + j0) * 2, pkd);
        }
        __syncthreads();
        if (t < 255 && tid == 0) st_flag(&flags[bid * 16], t);
    }
}

// =============== notes GEMM (MFMA): hist @ Wdec1.T + b -> out[:,1:,:] ===============
__global__ __launch_bounds__(256) void notes_mfma(
    const ushort* __restrict__ hist, const ushort* __restrict__ pk,
    const float* __restrict__ bd, float* __restrict__ out)
{
    __shared__ ushort hs[32 * 520];
    int m0 = blockIdx.x * 32;
    int tid = threadIdx.x;
    #pragma unroll
    for (int i = 0; i < 8; ++i) {
        int c = tid + i * 256;
        int row = c >> 6, off = c & 63;
        *(uint4*)((char*)hs + row * 1040 + off * 16) =
            *(const uint4*)(hist + (size_t)(m0 + row) * 512 + off * 8);
    }
    __syncthreads();
    int lane = tid & 63, wv = tid >> 6;
    int m = lane & 15, kb = lane >> 4;
    int nt0 = wv * 2;
    f32x4 acc00 = {0.f,0.f,0.f,0.f}, acc01 = {0.f,0.f,0.f,0.f};
    f32x4 acc10 = {0.f,0.f,0.f,0.f}, acc11 = {0.f,0.f,0.f,0.f};
    for (int ks = 0; ks < 16; ++ks) {
        bf16x8 a0 = *(const bf16x8*)&hs[m * 520 + ks * 32 + kb * 8];
        bf16x8 a1 = *(const bf16x8*)&hs[(16 + m) * 520 + ks * 32 + kb * 8];
        bf16x8 bf0 = *(const bf16x8*)&pk[(size_t)((nt0 * 16 + ks) * 64 + lane) * 8];
        bf16x8 bf1 = *(const bf16x8*)&pk[(size_t)(((nt0 + 1) * 16 + ks) * 64 + lane) * 8];
        acc00 = __builtin_amdgcn_mfma_f32_16x16x32_bf16(a0, bf0, acc00, 0, 0, 0);
        acc01 = __builtin_amdgcn_mfma_f32_16x16x32_bf16(a0, bf1, acc01, 0, 0, 0);
        acc10 = __builtin_amdgcn_mfma_f32_16x16x32_bf16(a1, bf0, acc10, 0, 0, 0);
        acc11 = __builtin_amdgcn_mfma_f32_16x16x32_bf16(a1, bf1, acc11, 0, 0, 0);
    }
    int n0 = nt0 * 16 + (lane & 15), n1 = (nt0 + 1) * 16 + (lane & 15);
    #pragma unroll
    for (int i = 0; i < 4; ++i) {
        int r0 = m0 + kb * 4 + i;
        int r1 = r0 + 16;
        int t0 = r0 >> 7, b0r = r0 & 127;
        int t1 = r1 >> 7, b1r = r1 & 127;
        out[((size_t)b0r * T_ + (t0 + 1)) * IN_ + n0] = acc00[i] + bd[n0];
        out[((size_t)b0r * T_ + (t0 + 1)) * IN_ + n1] = acc01[i] + bd[n1];
        out[((size_t)b1r * T_ + (t1 + 1)) * IN_ + n0] = acc10[i] + bd[n0];
        out[((size_t)b1r * T_ + (t1 + 1)) * IN_ + n1] = acc11[i] + bd[n1];
    }
}

// =============== MLP GEMM (fp32 A, bf16 tiled W) ===============
__global__ __launch_bounds__(256) void gemm_t4(
    const float* __restrict__ A, const ushort4* __restrict__ Wt,
    const float* __restrict__ bias, float* __restrict__ C,
    int M, int N, int K, int act)
{
    int nb = blockIdx.x, mb = blockIdx.y;
    int tid = threadIdx.x;
    int n = nb * 64 + (tid & 63);
    int mq = tid >> 6;
    int m0 = mb * 32;
    __shared__ float Asm[32][36];
    float acc[8];
    #pragma unroll
    for (int i = 0; i < 8; ++i) acc[i] = 0.f;
    for (int k0 = 0; k0 < K; k0 += 32) {
        int r = tid >> 3, c = (tid & 7) << 2;
        float4 v = *(const float4*)&A[(size_t)(m0 + r) * K + k0 + c];
        Asm[r][c] = v.x; Asm[r][c+1] = v.y; Asm[r][c+2] = v.z; Asm[r][c+3] = v.w;
        __syncthreads();
        #pragma unroll
        for (int kc = 0; kc < 8; ++kc) {
            float w0 = 0.f, w1 = 0.f, w2 = 0.f, w3 = 0.f;
            if (n < N) {
                ushort4 u = Wt[(size_t)((k0 >> 2) + kc) * N + n];
                w0 = bf2f(u.x); w1 = bf2f(u.y); w2 = bf2f(u.z); w3 = bf2f(u.w);
            }
            #pragma unroll
            for (int i = 0; i < 8; ++i) {
                int mm = mq * 8 + i;
                acc[i] += Asm[mm][kc*4+0]*w0 + Asm[mm][kc*4+1]*w1
                        + Asm[mm][kc*4+2]*w2 + Asm[mm][kc*4+3]*w3;
            }
        }
        __syncthreads();
    }
    if (n < N) {
        #pragma unroll
        for (int i = 0; i < 8; ++i) {
            int mm = m0 + mq * 8 + i;
            float v = acc[i] + bias[n];
            if (act == 1) v = (v >= 0.f) ? v : 0.01f * v;
            C[(size_t)mm * N + n] = v;
        }
    }
}

__global__ void z_k(const float* __restrict__ out, const float* __restrict__ eps,
                    const float* __restrict__ genre, float* __restrict__ zc) {
    int id = blockIdx.x * 256 + threadIdx.x;
    if (id >= B_ * L_) return;
    int b = id >> 8, c = id & 255;
    float v;
    if (c < LG_) {
        float mu = out[MU_OFF + (size_t)b * LG_ + c];
        float lv = out[LV_OFF + (size_t)b * LG_ + c];
        v = mu + expf(0.5f * lv) * eps[(size_t)b * LG_ + c];
    } else {
        v = genre[(size_t)b * G_ + (c - LG_)];
    }
    zc[id] = v;
}

// =============== host ===============
extern "C" void kernel_launch(void* const* d_in, const int* in_sizes, int n_in,
                              void* d_out, int out_size, void* d_ws, size_t ws_size,
                              hipStream_t stream) {
    (void)in_sizes; (void)n_in; (void)out_size; (void)ws_size;
    const float* x      = (const float*)d_in[0];
    const float* genre  = (const float*)d_in[1];
    const float* eps    = (const float*)d_in[2];
    const float* Wih_e  = (const float*)d_in[3];
    const float* Whh_e  = (const float*)d_in[4];
    const float* bih_e  = (const float*)d_in[5];
    const float* bhh_e  = (const float*)d_in[6];
    const float* Wih_be = (const float*)d_in[7];
    const float* Whh_be = (const float*)d_in[8];
    const float* bih_be = (const float*)d_in[9];
    const float* bhh_be = (const float*)d_in[10];
    const float* Wih_d  = (const float*)d_in[11];
    const float* Whh_d  = (const float*)d_in[12];
    const float* bih_d  = (const float*)d_in[13];
    const float* bhh_d  = (const float*)d_in[14];
    const float* W_mu0  = (const float*)d_in[15];
    const float* b_mu0  = (const float*)d_in[16];
    const float* W_mu1  = (const float*)d_in[17];
    const float* b_mu1  = (const float*)d_in[18];
    const float* W_lv0  = (const float*)d_in[19];
    const float* b_lv0  = (const float*)d_in[20];
    const float* W_lv1  = (const float*)d_in[21];
    const float* b_lv1  = (const float*)d_in[22];
    const float* W_lat0 = (const float*)d_in[23];
    const float* b_lat0 = (const float*)d_in[24];
    const float* W_lat1 = (const float*)d_in[25];
    const float* b_lat1 = (const float*)d_in[26];
    const float* W_dec1 = (const float*)d_in[27];
    const float* b_dec1 = (const float*)d_in[28];
    float* out = (float*)d_out;

    char* ws = (char*)d_ws;
    size_t off = 0;
    auto alloc = [&](size_t bytes) -> char* {
        char* p = ws + off;
        off = (off + bytes + 255) & ~(size_t)255;
        return p;
    };
    ushort* xb16  = (ushort*)alloc((size_t)T_ * B_ * 160 * 2);
    ushort* WE    = (ushort*)alloc((size_t)2 * 32 * 63 * 512 * 2);
    ushort* WD2   = (ushort*)alloc((size_t)32 * 64 * 512 * 2);
    ushort* WD1   = (ushort*)alloc((size_t)32 * 64 * 512 * 2);
    float*  Wf    = (float*)alloc((size_t)G3_ * H_ * 4);
    float*  bfi   = (float*)alloc(G3_ * 4);
    ushort* hb_e  = (ushort*)alloc((size_t)4 * 65536 * 2);
    ushort* hist  = (ushort*)alloc((size_t)255 * 65536 * 2);
    ushort* hdec0 = (ushort*)alloc((size_t)65536 * 2);
    ushort* pkdec = (ushort*)alloc((size_t)8192 * 8 * 2);
    int*    eflag = (int*)alloc((size_t)4096 * 4);
    int*    dflag = (int*)alloc((size_t)2048 * 4);
    float*  note0f= (float*)alloc((size_t)B_ * 128 * 4);
    float*  gi0   = (float*)alloc((size_t)B_ * G3_ * 4);
    float*  hidden= (float*)alloc((size_t)B_ * E_ * 4);
    float*  t0buf = (float*)alloc((size_t)B_ * E_ * 4);
    float*  t1buf = (float*)alloc((size_t)B_ * E_ * 4);
    float*  zcbuf = (float*)alloc((size_t)B_ * L_ * 4);
    float*  t2buf = (float*)alloc((size_t)B_ * L_ * 4);
    float*  t3buf = (float*)alloc((size_t)B_ * H_ * 4);

    ushort4* T_Wmu0  = (ushort4*)alloc((size_t)256 * E_ * 8);
    ushort4* T_Wmu1  = (ushort4*)alloc((size_t)256 * LG_ * 8);
    ushort4* T_Wlv0  = (ushort4*)alloc((size_t)256 * E_ * 8);
    ushort4* T_Wlv1  = (ushort4*)alloc((size_t)256 * LG_ * 8);
    ushort4* T_Wlat0 = (ushort4*)alloc((size_t)64 * L_ * 8);
    ushort4* T_Wlat1 = (ushort4*)alloc((size_t)64 * H_ * 8);
    ushort4* T_Wihd  = (ushort4*)alloc((size_t)32 * G3_ * 8);

    // ---- prep ----
    xpad_k<<<(T_ * B_ * 160 + 255) / 256, 256, 0, stream>>>(x, xb16);
    pack_we<<<1008, 256, 0, stream>>>(Wih_e, Whh_e, Wih_be, Whh_be, WE);
    wfused_k<<<(G3_ * H_ + 255) / 256, 256, 0, stream>>>(Wih_d, W_dec1, Wf);
    bfi_k<<<6, 256, 0, stream>>>(Wih_d, b_dec1, bih_d, bfi);
    pack_wd<<<512, 256, 0, stream>>>(Wf, Whh_d, WD2, 1);
    pack_wd<<<512, 256, 0, stream>>>(Wf, Whh_d, WD1, 0);
    pack_wdec<<<32, 256, 0, stream>>>(W_dec1, pkdec);
    zero_init<<<1024, 256, 0, stream>>>(hb_e, eflag, dflag);
    note0_k2<<<(B_ * IN_ + 255) / 256, 256, 0, stream>>>(x, out, note0f);

    auto tile = [&](const float* W, ushort4* dst, int N, int K) {
        int KC = (K + 3) / 4;
        tile_w<<<(KC * N + 255) / 256, 256, 0, stream>>>(W, dst, N, K, KC);
    };
    tile(W_mu0,  T_Wmu0,  E_,  E_);
    tile(W_mu1,  T_Wmu1,  LG_, E_);
    tile(W_lv0,  T_Wlv0,  E_,  E_);
    tile(W_lv1,  T_Wlv1,  LG_, E_);
    tile(W_lat0, T_Wlat0, L_,  L_);
    tile(W_lat1, T_Wlat1, H_,  L_);
    tile(Wih_d,  T_Wihd,  G3_, IN_);

    // ---- persistent bidirectional encoder (256 steps internally) ----
    enc_persist<<<256, 256, 0, stream>>>(xb16, WE, hb_e, hidden,
                                         bih_e, bhh_e, bih_be, bhh_be, eflag);

    // ---- MLP bottleneck ----
    {
        dim3 g1(16, 4), g2(4, 4), g3(4, 4), g4(8, 4), g5(24, 4);
        gemm_t4<<<g1, 256, 0, stream>>>(hidden, T_Wmu0, b_mu0, t0buf, B_, E_, E_, 1);
        gemm_t4<<<g2, 256, 0, stream>>>(t0buf, T_Wmu1, b_mu1, out + MU_OFF, B_, LG_, E_, 0);
        gemm_t4<<<g1, 256, 0, stream>>>(hidden, T_Wlv0, b_lv0, t1buf, B_, E_, E_, 1);
        gemm_t4<<<g2, 256, 0, stream>>>(t1buf, T_Wlv1, b_lv1, out + LV_OFF, B_, LG_, E_, 0);
        z_k<<<(B_ * L_ + 255) / 256, 256, 0, stream>>>(out, eps, genre, zcbuf);
        gemm_t4<<<g3, 256, 0, stream>>>(zcbuf, T_Wlat0, b_lat0, t2buf, B_, L_, L_, 1);
        gemm_t4<<<g4, 256, 0, stream>>>(t2buf, T_Wlat1, b_lat1, t3buf, B_, H_, L_, 0);
        gemm_t4<<<g5, 256, 0, stream>>>(note0f, T_Wihd, bih_d, gi0, B_, G3_, IN_, 0);
    }
    cvt_h0<<<(B_ * H_ + 255) / 256, 256, 0, stream>>>(t3buf, hdec0);

    // ---- persistent decoder (255 steps internally) ----
    dec_persist<<<128, 256, 0, stream>>>(hdec0, WD2, WD1, hist, t3buf,
                                         bfi, bhh_d, gi0, dflag);

    // ---- all notes (MFMA GEMM) ----
    notes_mfma<<<1020, 256, 0, stream>>>(hist, pkdec, b_dec1, out);
}